// Round 6
// baseline (261.991 us; speedup 1.0000x reference)
//
#include <hip/hip_runtime.h>
#include <hip/hip_bf16.h>

// ---------------- problem constants ----------------
// B=2 T2=9 T3=27 T1=243 P=17 K2=9 C=128
// CH = {48,96,192,384}, HW = {(96,72),(48,36),(24,18),(12,9)}, N=18
static constexpr int NQ_SIZE = 9517824;
static constexpr int NV_SIZE = 1057536;
static constexpr int NPOS    = 74358;   // 486*153 sampling points
static constexpr int M_CONV  = 8262;    // 2*243*17 rows of the conv GEMM

// E-map (projected feature, bf16, channels-last [n,h,w,128]) element offsets in ws
static constexpr long E0_OFF = 0;
static constexpr long E1_OFF = 15925248;            // 18*96*72*128
static constexpr long E2_OFF = E1_OFF + 3981312;    // 18*48*36*128
static constexpr long E3_OFF = E2_OFF + 995328;     // 18*24*18*128
static constexpr long E_END  = E3_OFF + 248832;     // 18*12*9*128  -> 21,150,720 elems

// prep kernel block-range segmentation (heavy GEMM segments first)
static constexpr int SEG_L3 = 18;             // M=108  K=384, 1 tile  x 18
static constexpr int SEG_L2 = SEG_L3 + 72;    // M=432  K=192, 4 tiles x 18
static constexpr int SEG_L1 = SEG_L2 + 252;   // M=1728 K=96, 14 tiles x 18
static constexpr int SEG_L0 = SEG_L1 + 972;   // M=6912 K=48, 54 tiles x 18
static constexpr int SEG_CT = SEG_L0 + 576;   // convT2: 147456/256
static constexpr int PREP_GRID = SEG_CT;      // 1890

typedef __attribute__((ext_vector_type(8))) short short8;   // 8 bf16 (4 VGPRs)
typedef __attribute__((ext_vector_type(4))) float floatx4;

__device__ __forceinline__ float bf2f(unsigned short u) {
    union { unsigned int i; float f; } v; v.i = ((unsigned)u) << 16; return v.f;
}
__device__ __forceinline__ unsigned short f2bf_rne(float f) {
    union { float f; unsigned int i; } v; v.f = f;
    unsigned int u = v.i;
    u += 0x7fffu + ((u >> 16) & 1u);
    return (unsigned short)(u >> 16);
}
__device__ __forceinline__ short8 pack8(const float* t) {
    union { unsigned short u[8]; short8 s; } r;
    #pragma unroll
    for (int i = 0; i < 8; ++i) r.u[i] = f2bf_rne(t[i]);
    return r.s;
}

// ---------------- projection GEMM body ----------------
// E[m, o] = sum_k A[k, m] * W[o, k]   (A = f_l slab, column-major in m; W = we_l)
// Tile M=128 x N=128 per block, 4 waves each owning 32 rows (2 A-frags).
// B staged to LDS per <=96-wide K-chunk (1 barrier/chunk), A loaded JIT per
// k-tile. Epilogue: acc -> LDS bf16 tile -> wide coalesced uint4 stores.
template<int K, int M, bool FULLM>
__device__ __forceinline__ void proj_body(
    const float* __restrict__ A, const float* __restrict__ W,
    unsigned short* __restrict__ Eo, int m0, int tid,
    unsigned short* __restrict__ shbuf)
{
    constexpr int KC      = (K < 96) ? K : 96;     // chunk width
    constexpr int KCPAD   = (KC + 31) & ~31;       // padded to mult of 32
    constexpr int KT      = KCPAD / 32;            // k-tiles per chunk
    constexpr int NCH     = K / KC;                // chunks
    constexpr bool NEEDPAD = (KCPAD != KC);        // only K=48

    unsigned short (*Bs)[104] = (unsigned short (*)[104])shbuf;

    const int lane = tid & 63;
    const int wave = tid >> 6;
    const int l15  = lane & 15;
    const int quad = lane >> 4;
    const int mg0  = m0 + wave * 32 + l15;
    const int mg1  = mg0 + 16;
    const bool v0  = FULLM || (mg0 < M);
    const bool v1  = FULLM || (mg1 < M);

    floatx4 acc[2][8];
    #pragma unroll
    for (int f = 0; f < 2; ++f)
        #pragma unroll
        for (int nt = 0; nt < 8; ++nt) acc[f][nt] = (floatx4){0.f, 0.f, 0.f, 0.f};

    // B staging split: thread -> o = tid>>1 (0..127), k-half = (tid&1)*KCPAD/2
    const int so  = tid >> 1;
    const int skb = (tid & 1) * (KCPAD / 2);

    #pragma unroll 1
    for (int ch = 0; ch < NCH; ++ch) {
        const int kc = ch * KC;
        if (ch) __syncthreads();     // previous chunk's readers done

        // ---- stage B chunk (fp32 global -> bf16 LDS), zero-pad beyond KC ----
        {
            const float* wp = W + (long)so * K + kc + skb;
            #pragma unroll
            for (int j = 0; j < KCPAD / 2; j += 8) {
                float t8[8];
                #pragma unroll
                for (int i = 0; i < 8; ++i)
                    t8[i] = (!NEEDPAD || (skb + j + i < KC)) ? wp[j + i] : 0.f;
                unsigned short u[8];
                #pragma unroll
                for (int i = 0; i < 8; ++i) u[i] = f2bf_rne(t8[i]);
                *(uint4*)&Bs[so][skb + j] = *(const uint4*)u;
            }
        }
        __syncthreads();

        // ---- barrier-free k-loop over this chunk (JIT A loads) ----
        #pragma unroll
        for (int kt = 0; kt < KT; ++kt) {
            const int kg = kc + kt * 32 + quad * 8;
            const float* ap = A + (long)kg * M + mg0;
            float a0[8], a1[8];
            if (FULLM && (!NEEDPAD || (kg + 8 <= K))) {
                #pragma unroll
                for (int j = 0; j < 8; ++j) {
                    a0[j] = ap[(long)j * M];
                    a1[j] = ap[(long)j * M + 16];
                }
            } else {
                #pragma unroll
                for (int j = 0; j < 8; ++j) {
                    a0[j] = 0.f; a1[j] = 0.f;
                    if (kg + j < K) {
                        if (v0) a0[j] = ap[(long)j * M];
                        if (v1) a1[j] = ap[(long)j * M + 16];
                    }
                }
            }
            short8 af0 = pack8(a0);
            short8 af1 = pack8(a1);
            #pragma unroll
            for (int nt = 0; nt < 8; ++nt) {
                short8 bf = *(const short8*)&Bs[nt * 16 + l15][kt * 32 + quad * 8];
                acc[0][nt] = __builtin_amdgcn_mfma_f32_16x16x32_bf16(af0, bf, acc[0][nt], 0, 0, 0);
                acc[1][nt] = __builtin_amdgcn_mfma_f32_16x16x32_bf16(af1, bf, acc[1][nt], 0, 0, 0);
            }
        }
    }

    // ---- epilogue: stage bf16 tile in LDS, then wide coalesced stores ----
    __syncthreads();    // all waves done reading Bs
    #pragma unroll
    for (int f = 0; f < 2; ++f) {
        #pragma unroll
        for (int nt = 0; nt < 8; ++nt) {
            #pragma unroll
            for (int r = 0; r < 4; ++r) {
                int row = wave * 32 + f * 16 + quad * 4 + r;
                shbuf[row * 128 + nt * 16 + l15] = f2bf_rne(acc[f][nt][r]);
            }
        }
    }
    __syncthreads();
    const uint4* sb4 = (const uint4*)shbuf;
    uint4* eo4 = (uint4*)(Eo + (long)m0 * 128);
    #pragma unroll
    for (int j = 0; j < 8; ++j) {
        int off16 = wave * 512 + j * 64 + lane;     // uint4 index, 16 per row
        if (FULLM || (m0 + (off16 >> 4) < M))
            eo4[off16] = sb4[off16];
    }
}

// ---------------- fused prep kernel: projections + convT2 ----------------
__global__ __launch_bounds__(256) void prep_k(
    const float* __restrict__ f0, const float* __restrict__ f1,
    const float* __restrict__ f2, const float* __restrict__ f3,
    const float* __restrict__ we0, const float* __restrict__ we1,
    const float* __restrict__ we2, const float* __restrict__ we3,
    const float* __restrict__ conv_w, unsigned short* __restrict__ convT2,
    unsigned short* __restrict__ Ebase)
{
    __shared__ unsigned short shbuf[128 * 128];   // 32KB: B-stage / epilogue tile
    const int bid = blockIdx.x;
    const int tid = threadIdx.x;

    if (bid < SEG_L0) {
        if (bid < SEG_L3) {
            int n = bid;
            proj_body<384, 108, false>(f3 + (long)n * 384 * 108, we3,
                Ebase + E3_OFF + (long)n * 108 * 128, 0, tid, shbuf);
        } else if (bid < SEG_L2) {
            int r = bid - SEG_L3; int n = r >> 2, t = r & 3;
            const float* A = f2 + (long)n * 192 * 432;
            unsigned short* Eo = Ebase + E2_OFF + (long)n * 432 * 128;
            if (t < 3) proj_body<192, 432, true >(A, we2, Eo, t * 128, tid, shbuf);
            else       proj_body<192, 432, false>(A, we2, Eo, t * 128, tid, shbuf);
        } else if (bid < SEG_L1) {
            int r = bid - SEG_L2; int n = r / 14, t = r - n * 14;
            const float* A = f1 + (long)n * 96 * 1728;
            unsigned short* Eo = Ebase + E1_OFF + (long)n * 1728 * 128;
            if (t < 13) proj_body<96, 1728, true >(A, we1, Eo, t * 128, tid, shbuf);
            else        proj_body<96, 1728, false>(A, we1, Eo, t * 128, tid, shbuf);
        } else {
            int r = bid - SEG_L1; int n = r / 54, t = r - n * 54;
            proj_body<48, 6912, true>(f0 + (long)n * 48 * 6912, we0,
                Ebase + E0_OFF + (long)n * 6912 * 128, t * 128, tid, shbuf);
        }
    } else {
        // ---- convT2 transpose+cast ----
        int idx = (bid - SEG_L0) * 256 + tid;
        if (idx < 147456) {
            int o = idx / 1152, kk = idx - o * 1152;
            int k2 = kk >> 7, c = kk & 127;
            convT2[idx] = f2bf_rne(conv_w[o * 1152 + c * 9 + k2]);
        }
    }
}

// ---------------- fused gather + sampling + blend + conv -> nq, nv, samp ----
// One block per HALF-bt1 (972 blocks, bijective XCD swizzle: 972 = 8*121+4).
//  Phase 1: attention weights (17x2 softmax) + bias-sum -> LDS.
//  Phase 2: 16 lanes/position, positions q in [qbase, qbase+NQR):
//           inline sampling offsets, 4-level bilinear gather, blend ->
//           nq (global fp32) AND nq_lds (bf16, padded rows).
//  Phase 3: conv GEMM from LDS: nv[bt1*17+p][o] over this half's p-rows;
//           conv row p needs exactly nq rows q = p*9 + k2 (all in this half).
__global__ __launch_bounds__(256) void gc_k(
    const unsigned short* __restrict__ Ebase,
    const unsigned short* __restrict__ convT2,
    const float* __restrict__ query, const float* __restrict__ key,
    const float* __restrict__ value,
    const float* __restrict__ w_off, const float* __restrict__ b_off,
    const float* __restrict__ w_attn, const float* __restrict__ b_attn,
    const float* __restrict__ be0, const float* __restrict__ be1,
    const float* __restrict__ be2, const float* __restrict__ be3,
    const float* __restrict__ conv_b,
    float* __restrict__ nq, float* __restrict__ nv, float* __restrict__ samp)
{
    __shared__ float aw_lds[17][2];
    __shared__ float besum_lds[128];
    __shared__ unsigned short nq_lds[81 * 136];   // rows padded 128->136 (16B rows)

    const int tid = threadIdx.x;
    // bijective XCD swizzle (972 blocks, 8 XCDs: first 4 get 122, rest 121)
    const int xcd = blockIdx.x & 7, slot = blockIdx.x >> 3;
    const int logical = (xcd < 4) ? xcd * 122 + slot : 488 + (xcd - 4) * 121 + slot;
    const int bt1   = logical >> 1;
    const int half  = logical & 1;
    const int qbase = half * 81;
    const int NQR   = half ? 72 : 81;   // q-rows this block owns
    const int NP    = half ? 8 : 9;     // conv p-rows this block owns
    const int pbase = half * 9;

    const int bb = bt1 / 243, t1 = bt1 - bb * 243, t2 = t1 / 27;
    const int n  = bb * 9 + t2;

    // ---- phase 1: attention weights + bias-sum ----
    if (tid < 136) {
        int p = tid >> 3, o = (tid >> 2) & 1, qt = tid & 3;
        const float* vrow = value + ((long)bt1 * 17 + p) * 128 + qt * 32;
        const float* wrow = w_attn + o * 128 + qt * 32;
        float s = 0.f;
        #pragma unroll
        for (int c = 0; c < 32; c += 4) {
            float4 v = *(const float4*)(vrow + c);
            float4 w = *(const float4*)(wrow + c);
            s += v.x * w.x + v.y * w.y + v.z * w.z + v.w * w.w;
        }
        s += __shfl_xor(s, 1);
        s += __shfl_xor(s, 2);
        s += b_attn[o];
        float so = __shfl_xor(s, 4);     // partner o within same 8-group
        float m  = fmaxf(s, so);
        float e  = __expf(s - m), eo = __expf(so - m);
        if (qt == 0) aw_lds[p][o] = e / (e + eo);
    }
    if (tid >= 128) {
        int c = tid - 128;
        besum_lds[c] = be0[c] + be1[c] + be2[c] + be3[c];
    }
    __syncthreads();

    // ---- phase 2: gather positions ----
    const int grp = tid >> 4, l16 = tid & 15, c8 = l16 << 3;
    const float4 w0a = *(const float4*)(w_off + c8);
    const float4 w0b = *(const float4*)(w_off + c8 + 4);
    const float4 w1a = *(const float4*)(w_off + 128 + c8);
    const float4 w1b = *(const float4*)(w_off + 128 + c8 + 4);
    const float bo0 = b_off[0], bo1 = b_off[1];
    const float4 bs0 = *(const float4*)(besum_lds + c8);
    const float4 bs1 = *(const float4*)(besum_lds + c8 + 4);
    const long Eoffs[4] = {E0_OFF, E1_OFF, E2_OFF, E3_OFF};
    const int Hs[4] = {96, 48, 24, 12}, Wd[4] = {72, 36, 18, 9};

    for (int ql = grp; ql < NQR; ql += 16) {
        const int q = qbase + ql;
        const long qglob = (long)bt1 * 153 + q;
        const long qi = qglob * 128 + c8;
        const float4 qv0 = *(const float4*)(query + qi);
        const float4 qv1 = *(const float4*)(query + qi + 4);

        float s0 = qv0.x*w0a.x + qv0.y*w0a.y + qv0.z*w0a.z + qv0.w*w0a.w
                 + qv1.x*w0b.x + qv1.y*w0b.y + qv1.z*w0b.z + qv1.w*w0b.w;
        float s1 = qv0.x*w1a.x + qv0.y*w1a.y + qv0.z*w1a.z + qv0.w*w1a.w
                 + qv1.x*w1b.x + qv1.y*w1b.y + qv1.z*w1b.z + qv1.w*w1b.w;
        #pragma unroll
        for (int m = 8; m >= 1; m >>= 1) {
            s0 += __shfl_xor(s0, m);
            s1 += __shfl_xor(s1, m);
        }
        const int paw = q % 17;
        const float aw0 = aw_lds[paw][0], aw1 = aw_lds[paw][1];
        const float2 kv = *(const float2*)(key + qglob * 2);
        const float gx = kv.x + tanhf(s0 + bo0) * aw0;
        const float gy = kv.y + tanhf(s1 + bo1) * aw1;
        if (l16 == 0) *(float2*)(samp + qglob * 2) = (float2){gx, gy};

        float acc[8];
        #pragma unroll
        for (int j = 0; j < 8; ++j) acc[j] = 0.f;
        #pragma unroll
        for (int l = 0; l < 4; ++l) {
            const int H = Hs[l], W = Wd[l];
            const unsigned short* E = Ebase + Eoffs[l] + (long)n * H * W * 128 + c8;
            float ix = ((gx + 1.f) * (float)W - 1.f) * 0.5f;
            float iy = ((gy + 1.f) * (float)H - 1.f) * 0.5f;
            float fx0 = floorf(ix), fy0 = floorf(iy);
            int x0 = (int)fx0, y0 = (int)fy0, x1 = x0 + 1, y1 = y0 + 1;
            float wx1 = ix - fx0, wx0 = 1.f - wx1;
            float wy1 = iy - fy0, wy0 = 1.f - wy1;
            bool vy0 = (unsigned)y0 < (unsigned)H, vy1 = (unsigned)y1 < (unsigned)H;
            bool vx0 = (unsigned)x0 < (unsigned)W, vx1 = (unsigned)x1 < (unsigned)W;
            float w00 = (vy0 && vx0) ? wy0 * wx0 : 0.f;
            float w01 = (vy0 && vx1) ? wy0 * wx1 : 0.f;
            float w10 = (vy1 && vx0) ? wy1 * wx0 : 0.f;
            float w11 = (vy1 && vx1) ? wy1 * wx1 : 0.f;
            int yc0 = min(max(y0, 0), H - 1), yc1 = min(max(y1, 0), H - 1);
            int xc0 = min(max(x0, 0), W - 1), xc1 = min(max(x1, 0), W - 1);
            short8 v00 = *(const short8*)(E + ((long)yc0 * W + xc0) * 128);
            short8 v01 = *(const short8*)(E + ((long)yc0 * W + xc1) * 128);
            short8 v10 = *(const short8*)(E + ((long)yc1 * W + xc0) * 128);
            short8 v11 = *(const short8*)(E + ((long)yc1 * W + xc1) * 128);
            #pragma unroll
            for (int j = 0; j < 8; ++j) {
                float a = acc[j];
                a = fmaf(w00, bf2f((unsigned short)v00[j]), a);
                a = fmaf(w01, bf2f((unsigned short)v01[j]), a);
                a = fmaf(w10, bf2f((unsigned short)v10[j]), a);
                a = fmaf(w11, bf2f((unsigned short)v11[j]), a);
                acc[j] = a;
            }
        }

        float ov[8];
        ov[0] = 0.1f * (0.25f * (acc[0] + bs0.x)) + 0.9f * qv0.x;
        ov[1] = 0.1f * (0.25f * (acc[1] + bs0.y)) + 0.9f * qv0.y;
        ov[2] = 0.1f * (0.25f * (acc[2] + bs0.z)) + 0.9f * qv0.z;
        ov[3] = 0.1f * (0.25f * (acc[3] + bs0.w)) + 0.9f * qv0.w;
        ov[4] = 0.1f * (0.25f * (acc[4] + bs1.x)) + 0.9f * qv1.x;
        ov[5] = 0.1f * (0.25f * (acc[5] + bs1.y)) + 0.9f * qv1.y;
        ov[6] = 0.1f * (0.25f * (acc[6] + bs1.z)) + 0.9f * qv1.z;
        ov[7] = 0.1f * (0.25f * (acc[7] + bs1.w)) + 0.9f * qv1.w;
        *(float4*)(nq + qi)     = (float4){ov[0], ov[1], ov[2], ov[3]};
        *(float4*)(nq + qi + 4) = (float4){ov[4], ov[5], ov[6], ov[7]};
        // bf16 copy into LDS for the conv phase (same rounding conv used before)
        unsigned short u[8];
        #pragma unroll
        for (int j = 0; j < 8; ++j) u[j] = f2bf_rne(ov[j]);
        *(uint4*)&nq_lds[ql * 136 + c8] = *(const uint4*)u;
    }
    __syncthreads();

    // ---- phase 3: conv GEMM from LDS ----
    // D[p][o] = sum_{k2,c} nq_lds[p*9+k2][c] * convT2[o][k2*128+c]
    const int lane = tid & 63, wave = tid >> 6;
    const int l15 = lane & 15, quad = lane >> 4;
    const int colb = wave * 32;
    floatx4 cacc[2];
    cacc[0] = (floatx4){0.f, 0.f, 0.f, 0.f};
    cacc[1] = cacc[0];
    const bool avalid = l15 < NP;

    #pragma unroll 4
    for (int ks = 0; ks < 36; ++ks) {
        const int kk0 = ks * 32 + quad * 8;
        const int k2 = kk0 >> 7, c0 = kk0 & 127;
        short8 af = (short8){0, 0, 0, 0, 0, 0, 0, 0};
        if (avalid)
            af = *(const short8*)&nq_lds[(l15 * 9 + k2) * 136 + c0];
        #pragma unroll
        for (int nt = 0; nt < 2; ++nt) {
            short8 bf = *(const short8*)(convT2 + (long)(colb + nt * 16 + l15) * 1152 + kk0);
            cacc[nt] = __builtin_amdgcn_mfma_f32_16x16x32_bf16(af, bf, cacc[nt], 0, 0, 0);
        }
    }

    #pragma unroll
    for (int nt = 0; nt < 2; ++nt) {
        const int col = colb + nt * 16 + l15;
        const float bias = conv_b[col];
        #pragma unroll
        for (int r = 0; r < 4; ++r) {
            const int p = quad * 4 + r;
            if (p < NP)
                nv[((long)bt1 * 17 + pbase + p) * 128 + col] = cacc[nt][r] + bias;
        }
    }
}

extern "C" void kernel_launch(void* const* d_in, const int* in_sizes, int n_in,
                              void* d_out, int out_size, void* d_ws, size_t ws_size,
                              hipStream_t stream) {
    const float* f0     = (const float*)d_in[0];
    const float* f1     = (const float*)d_in[1];
    const float* f2     = (const float*)d_in[2];
    const float* f3     = (const float*)d_in[3];
    const float* query  = (const float*)d_in[4];
    const float* key    = (const float*)d_in[5];
    const float* value  = (const float*)d_in[6];
    const float* w_off  = (const float*)d_in[7];
    const float* b_off  = (const float*)d_in[8];
    const float* w_attn = (const float*)d_in[9];
    const float* b_attn = (const float*)d_in[10];
    const float* we0    = (const float*)d_in[11];
    const float* be0    = (const float*)d_in[12];
    const float* we1    = (const float*)d_in[13];
    const float* be1    = (const float*)d_in[14];
    const float* we2    = (const float*)d_in[15];
    const float* be2    = (const float*)d_in[16];
    const float* we3    = (const float*)d_in[17];
    const float* be3    = (const float*)d_in[18];
    const float* conv_w = (const float*)d_in[19];
    const float* conv_b = (const float*)d_in[20];

    float* out  = (float*)d_out;
    float* nq   = out;                       // new_query
    float* nv   = out + NQ_SIZE;             // new_value
    float* samp = out + NQ_SIZE + NV_SIZE;   // sampling_positions

    // ws layout: E maps (bf16, 21,150,720) | convT2 (bf16, 147,456)
    unsigned short* Ebase  = (unsigned short*)d_ws;
    unsigned short* convT2 = Ebase + E_END;

    // 1. prep: projections (MFMA, JIT-A, LDS epilogue) + convT2
    prep_k<<<PREP_GRID, 256, 0, stream>>>(
        f0, f1, f2, f3, we0, we1, we2, we3, conv_w, convT2, Ebase);

    // 2. fused gather + sampling + blend + conv (972 blocks, half-bt1 each)
    gc_k<<<972, 256, 0, stream>>>(
        Ebase, convT2, query, key, value, w_off, b_off, w_attn, b_attn,
        be0, be1, be2, be3, conv_b, nq, nv, samp);
}

// Round 7
// 212.598 us; speedup vs baseline: 1.2323x; 1.2323x over previous
//
#include <hip/hip_runtime.h>
#include <hip/hip_bf16.h>

// ---------------- problem constants ----------------
// B=2 T2=9 T3=27 T1=243 P=17 K2=9 C=128
// CH = {48,96,192,384}, HW = {(96,72),(48,36),(24,18),(12,9)}, N=18
static constexpr int NQ_SIZE = 9517824;
static constexpr int NV_SIZE = 1057536;
static constexpr int NPOS    = 74358;   // 486*153 sampling points
static constexpr int M_CONV  = 8262;    // 2*243*17 rows of the conv GEMM

// E-map (projected feature, bf16, channels-last [n,h,w,128]) element offsets in ws
static constexpr long E0_OFF = 0;
static constexpr long E1_OFF = 15925248;            // 18*96*72*128
static constexpr long E2_OFF = E1_OFF + 3981312;    // 18*48*36*128
static constexpr long E3_OFF = E2_OFF + 995328;     // 18*24*18*128
static constexpr long E_END  = E3_OFF + 248832;     // 18*12*9*128  -> 21,150,720 elems

// prep kernel block-range segmentation (heavy GEMM segments first)
static constexpr int SEG_L3 = 18;             // M=108  K=384, 1 tile  x 18
static constexpr int SEG_L2 = SEG_L3 + 72;    // M=432  K=192, 4 tiles x 18
static constexpr int SEG_L1 = SEG_L2 + 252;   // M=1728 K=96, 14 tiles x 18
static constexpr int SEG_L0 = SEG_L1 + 972;   // M=6912 K=48, 54 tiles x 18
static constexpr int SEG_AW = SEG_L0 + 65;    // attention weights: 16524 threads
static constexpr int SEG_CT = SEG_AW + 576;   // convT2: 147456/256
static constexpr int PREP_GRID = SEG_CT + 1;  // +1 block: bias-sum table

typedef __attribute__((ext_vector_type(8))) short short8;   // 8 bf16 (4 VGPRs)
typedef __attribute__((ext_vector_type(4))) float floatx4;

__device__ __forceinline__ float bf2f(unsigned short u) {
    union { unsigned int i; float f; } v; v.i = ((unsigned)u) << 16; return v.f;
}
__device__ __forceinline__ unsigned short f2bf_rne(float f) {
    union { float f; unsigned int i; } v; v.f = f;
    unsigned int u = v.i;
    u += 0x7fffu + ((u >> 16) & 1u);
    return (unsigned short)(u >> 16);
}
__device__ __forceinline__ short8 pack8(const float* t) {
    union { unsigned short u[8]; short8 s; } r;
    #pragma unroll
    for (int i = 0; i < 8; ++i) r.u[i] = f2bf_rne(t[i]);
    return r.s;
}

// ---------------- projection GEMM body ----------------
// E[m, o] = sum_k A[k, m] * W[o, k]   (A = f_l slab, column-major in m; W = we_l)
// Tile M=128 x N=128 per block, 4 waves each owning 32 rows (2 A-frags).
// B staged to LDS per <=96-wide K-chunk (1 barrier/chunk), A loaded JIT per
// k-tile. Epilogue: acc -> LDS bf16 tile -> wide coalesced uint4 stores.
template<int K, int M, bool FULLM>
__device__ __forceinline__ void proj_body(
    const float* __restrict__ A, const float* __restrict__ W,
    unsigned short* __restrict__ Eo, int m0, int tid,
    unsigned short* __restrict__ shbuf)
{
    constexpr int KC      = (K < 96) ? K : 96;     // chunk width
    constexpr int KCPAD   = (KC + 31) & ~31;       // padded to mult of 32
    constexpr int KT      = KCPAD / 32;            // k-tiles per chunk
    constexpr int NCH     = K / KC;                // chunks
    constexpr bool NEEDPAD = (KCPAD != KC);        // only K=48

    unsigned short (*Bs)[104] = (unsigned short (*)[104])shbuf;

    const int lane = tid & 63;
    const int wave = tid >> 6;
    const int l15  = lane & 15;
    const int quad = lane >> 4;
    const int mg0  = m0 + wave * 32 + l15;
    const int mg1  = mg0 + 16;
    const bool v0  = FULLM || (mg0 < M);
    const bool v1  = FULLM || (mg1 < M);

    floatx4 acc[2][8];
    #pragma unroll
    for (int f = 0; f < 2; ++f)
        #pragma unroll
        for (int nt = 0; nt < 8; ++nt) acc[f][nt] = (floatx4){0.f, 0.f, 0.f, 0.f};

    // B staging split: thread -> o = tid>>1 (0..127), k-half = (tid&1)*KCPAD/2
    const int so  = tid >> 1;
    const int skb = (tid & 1) * (KCPAD / 2);

    #pragma unroll 1
    for (int ch = 0; ch < NCH; ++ch) {
        const int kc = ch * KC;
        if (ch) __syncthreads();     // previous chunk's readers done

        // ---- stage B chunk (fp32 global -> bf16 LDS), zero-pad beyond KC ----
        {
            const float* wp = W + (long)so * K + kc + skb;
            #pragma unroll
            for (int j = 0; j < KCPAD / 2; j += 8) {
                float t8[8];
                #pragma unroll
                for (int i = 0; i < 8; ++i)
                    t8[i] = (!NEEDPAD || (skb + j + i < KC)) ? wp[j + i] : 0.f;
                unsigned short u[8];
                #pragma unroll
                for (int i = 0; i < 8; ++i) u[i] = f2bf_rne(t8[i]);
                *(uint4*)&Bs[so][skb + j] = *(const uint4*)u;
            }
        }
        __syncthreads();

        // ---- barrier-free k-loop over this chunk (JIT A loads) ----
        #pragma unroll
        for (int kt = 0; kt < KT; ++kt) {
            const int kg = kc + kt * 32 + quad * 8;
            const float* ap = A + (long)kg * M + mg0;
            float a0[8], a1[8];
            if (FULLM && (!NEEDPAD || (kg + 8 <= K))) {
                #pragma unroll
                for (int j = 0; j < 8; ++j) {
                    a0[j] = ap[(long)j * M];
                    a1[j] = ap[(long)j * M + 16];
                }
            } else {
                #pragma unroll
                for (int j = 0; j < 8; ++j) {
                    a0[j] = 0.f; a1[j] = 0.f;
                    if (kg + j < K) {
                        if (v0) a0[j] = ap[(long)j * M];
                        if (v1) a1[j] = ap[(long)j * M + 16];
                    }
                }
            }
            short8 af0 = pack8(a0);
            short8 af1 = pack8(a1);
            #pragma unroll
            for (int nt = 0; nt < 8; ++nt) {
                short8 bf = *(const short8*)&Bs[nt * 16 + l15][kt * 32 + quad * 8];
                acc[0][nt] = __builtin_amdgcn_mfma_f32_16x16x32_bf16(af0, bf, acc[0][nt], 0, 0, 0);
                acc[1][nt] = __builtin_amdgcn_mfma_f32_16x16x32_bf16(af1, bf, acc[1][nt], 0, 0, 0);
            }
        }
    }

    // ---- epilogue: stage bf16 tile in LDS, then wide coalesced stores ----
    __syncthreads();    // all waves done reading Bs
    #pragma unroll
    for (int f = 0; f < 2; ++f) {
        #pragma unroll
        for (int nt = 0; nt < 8; ++nt) {
            #pragma unroll
            for (int r = 0; r < 4; ++r) {
                int row = wave * 32 + f * 16 + quad * 4 + r;
                shbuf[row * 128 + nt * 16 + l15] = f2bf_rne(acc[f][nt][r]);
            }
        }
    }
    __syncthreads();
    const uint4* sb4 = (const uint4*)shbuf;
    uint4* eo4 = (uint4*)(Eo + (long)m0 * 128);
    #pragma unroll
    for (int j = 0; j < 8; ++j) {
        int off16 = wave * 512 + j * 64 + lane;     // uint4 index, 16 per row
        if (FULLM || (m0 + (off16 >> 4) < M))
            eo4[off16] = sb4[off16];
    }
}

// ---------------- fused prep kernel ----------------
__global__ __launch_bounds__(256) void prep_k(
    const float* __restrict__ f0, const float* __restrict__ f1,
    const float* __restrict__ f2, const float* __restrict__ f3,
    const float* __restrict__ we0, const float* __restrict__ we1,
    const float* __restrict__ we2, const float* __restrict__ we3,
    const float* __restrict__ conv_w, unsigned short* __restrict__ convT2,
    const float* __restrict__ value,
    const float* __restrict__ w_attn, const float* __restrict__ b_attn,
    const float* __restrict__ be0, const float* __restrict__ be1,
    const float* __restrict__ be2, const float* __restrict__ be3,
    float* __restrict__ awbuf, float* __restrict__ besum,
    unsigned short* __restrict__ Ebase)
{
    __shared__ unsigned short shbuf[128 * 128];   // 32KB: B-stage / epilogue tile
    const int bid = blockIdx.x;
    const int tid = threadIdx.x;

    if (bid < SEG_L0) {
        if (bid < SEG_L3) {
            int n = bid;
            proj_body<384, 108, false>(f3 + (long)n * 384 * 108, we3,
                Ebase + E3_OFF + (long)n * 108 * 128, 0, tid, shbuf);
        } else if (bid < SEG_L2) {
            int r = bid - SEG_L3; int n = r >> 2, t = r & 3;
            const float* A = f2 + (long)n * 192 * 432;
            unsigned short* Eo = Ebase + E2_OFF + (long)n * 432 * 128;
            if (t < 3) proj_body<192, 432, true >(A, we2, Eo, t * 128, tid, shbuf);
            else       proj_body<192, 432, false>(A, we2, Eo, t * 128, tid, shbuf);
        } else if (bid < SEG_L1) {
            int r = bid - SEG_L2; int n = r / 14, t = r - n * 14;
            const float* A = f1 + (long)n * 96 * 1728;
            unsigned short* Eo = Ebase + E1_OFF + (long)n * 1728 * 128;
            if (t < 13) proj_body<96, 1728, true >(A, we1, Eo, t * 128, tid, shbuf);
            else        proj_body<96, 1728, false>(A, we1, Eo, t * 128, tid, shbuf);
        } else {
            int r = bid - SEG_L1; int n = r / 54, t = r - n * 54;
            proj_body<48, 6912, true>(f0 + (long)n * 48 * 6912, we0,
                Ebase + E0_OFF + (long)n * 6912 * 128, t * 128, tid, shbuf);
        }
    } else if (bid < SEG_AW) {
        // ---- attention weights: 2 threads per (bt1,p) row, shfl partner swap ----
        int t = (bid - SEG_L0) * 256 + tid;
        if (t < 16524) {
            int rp = t >> 1, o = t & 1;
            const float* vrow = value + (long)rp * 128;
            const float* wrow = w_attn + o * 128;
            float s = 0.f;
            for (int c = 0; c < 128; c += 4) {
                float4 v = *(const float4*)(vrow + c);
                float4 w = *(const float4*)(wrow + c);
                s += v.x * w.x + v.y * w.y + v.z * w.z + v.w * w.w;
            }
            s += b_attn[o];
            float so = __shfl_xor(s, 1);
            float m = fmaxf(s, so);
            float e = __expf(s - m), eo = __expf(so - m);
            awbuf[t] = e / (e + eo);
        }
    } else if (bid < SEG_CT) {
        // ---- convT2 transpose+cast ----
        int idx = (bid - SEG_AW) * 256 + tid;
        if (idx < 147456) {
            int o = idx / 1152, kk = idx - o * 1152;
            int k2 = kk >> 7, c = kk & 127;
            convT2[idx] = f2bf_rne(conv_w[o * 1152 + c * 9 + k2]);
        }
    } else {
        // ---- bias-sum table: besum[c] = be0+be1+be2+be3 ----
        if (tid < 128)
            besum[tid] = be0[tid] + be1[tid] + be2[tid] + be3[tid];
    }
}

// ---------------- gather + sampling + mean + blend -> new_query, samp ----------------
// 16 lanes/position, 8 channels/lane (ushort8 16B E loads). Branchless corner
// handling. XCD-aware block swizzle (4648 = 8 x 581).  [round-4 best config]
__global__ __launch_bounds__(256) void gather_k(
    const unsigned short* __restrict__ Ebase,
    const float* __restrict__ query, const float* __restrict__ key,
    const float* __restrict__ w_off, const float* __restrict__ b_off,
    const float* __restrict__ awbuf, const float* __restrict__ besum,
    float* __restrict__ nq, float* __restrict__ samp)
{
    const int tid = threadIdx.x;
    const int li  = (blockIdx.x & 7) * 581 + (blockIdx.x >> 3);   // XCD swizzle
    const int pos = li * 16 + (tid >> 4);
    if (pos >= NPOS) return;
    const int l16 = tid & 15;
    const int c8  = l16 << 3;

    const int bt1 = pos / 153, q = pos - bt1 * 153;
    const int b  = bt1 / 243, t1 = bt1 - b * 243;
    const int t2 = t1 / 27,  t3 = t1 - t2 * 27;
    const int n  = b * 9 + t2;
    const int p  = q % 17;

    // query row (used for both the offset dot-product and the final blend)
    const long qi = (long)pos * 128 + c8;
    const float4 qv0 = *(const float4*)(query + qi);
    const float4 qv1 = *(const float4*)(query + qi + 4);

    // ---- sampling offsets: off_o = tanh(q . w_off[o] + b_off[o]) ----
    float4 w0a = *(const float4*)(w_off + c8);
    float4 w0b = *(const float4*)(w_off + c8 + 4);
    float4 w1a = *(const float4*)(w_off + 128 + c8);
    float4 w1b = *(const float4*)(w_off + 128 + c8 + 4);
    float s0 = qv0.x * w0a.x + qv0.y * w0a.y + qv0.z * w0a.z + qv0.w * w0a.w
             + qv1.x * w0b.x + qv1.y * w0b.y + qv1.z * w0b.z + qv1.w * w0b.w;
    float s1 = qv0.x * w1a.x + qv0.y * w1a.y + qv0.z * w1a.z + qv0.w * w1a.w
             + qv1.x * w1b.x + qv1.y * w1b.y + qv1.z * w1b.z + qv1.w * w1b.w;
    #pragma unroll
    for (int m = 8; m >= 1; m >>= 1) {
        s0 += __shfl_xor(s0, m);
        s1 += __shfl_xor(s1, m);
    }
    const float aw0 = awbuf[(bt1 * 17 + p) * 2];
    const float aw1 = awbuf[(bt1 * 17 + p) * 2 + 1];
    const float off0 = tanhf(s0 + b_off[0]);
    const float off1 = tanhf(s1 + b_off[1]);
    const long kidx = (((long)n * 27 + t3) * 153 + q) * 2;
    const float gx = key[kidx]     + off0 * aw0;
    const float gy = key[kidx + 1] + off1 * aw1;
    if (l16 == 0) *(float2*)(samp + kidx) = (float2){gx, gy};

    // ---- 4-level bilinear gather (branchless, clamped + zero-weight) ----
    float acc[8];
    #pragma unroll
    for (int j = 0; j < 8; ++j) acc[j] = 0.f;
    const long Eoffs[4] = {E0_OFF, E1_OFF, E2_OFF, E3_OFF};
    const int Hs[4] = {96, 48, 24, 12}, Wd[4] = {72, 36, 18, 9};
    #pragma unroll
    for (int l = 0; l < 4; ++l) {
        const int H = Hs[l], W = Wd[l];
        const unsigned short* E = Ebase + Eoffs[l] + (long)n * H * W * 128 + c8;
        float ix = ((gx + 1.f) * (float)W - 1.f) * 0.5f;
        float iy = ((gy + 1.f) * (float)H - 1.f) * 0.5f;
        float fx0 = floorf(ix), fy0 = floorf(iy);
        int x0 = (int)fx0, y0 = (int)fy0;
        int x1 = x0 + 1, y1 = y0 + 1;
        float wx1 = ix - fx0, wx0 = 1.f - wx1;
        float wy1 = iy - fy0, wy0 = 1.f - wy1;
        bool vy0 = (unsigned)y0 < (unsigned)H, vy1 = (unsigned)y1 < (unsigned)H;
        bool vx0 = (unsigned)x0 < (unsigned)W, vx1 = (unsigned)x1 < (unsigned)W;
        float w00 = (vy0 && vx0) ? wy0 * wx0 : 0.f;
        float w01 = (vy0 && vx1) ? wy0 * wx1 : 0.f;
        float w10 = (vy1 && vx0) ? wy1 * wx0 : 0.f;
        float w11 = (vy1 && vx1) ? wy1 * wx1 : 0.f;
        int yc0 = min(max(y0, 0), H - 1), yc1 = min(max(y1, 0), H - 1);
        int xc0 = min(max(x0, 0), W - 1), xc1 = min(max(x1, 0), W - 1);
        short8 v00 = *(const short8*)(E + ((long)yc0 * W + xc0) * 128);
        short8 v01 = *(const short8*)(E + ((long)yc0 * W + xc1) * 128);
        short8 v10 = *(const short8*)(E + ((long)yc1 * W + xc0) * 128);
        short8 v11 = *(const short8*)(E + ((long)yc1 * W + xc1) * 128);
        #pragma unroll
        for (int j = 0; j < 8; ++j) {
            float a = acc[j];
            a = fmaf(w00, bf2f((unsigned short)v00[j]), a);
            a = fmaf(w01, bf2f((unsigned short)v01[j]), a);
            a = fmaf(w10, bf2f((unsigned short)v10[j]), a);
            a = fmaf(w11, bf2f((unsigned short)v11[j]), a);
            acc[j] = a;
        }
    }
    const float4 bs0 = *(const float4*)(besum + c8);
    const float4 bs1 = *(const float4*)(besum + c8 + 4);
    float4 o0, o1;
    o0.x = 0.1f * (0.25f * (acc[0] + bs0.x)) + 0.9f * qv0.x;
    o0.y = 0.1f * (0.25f * (acc[1] + bs0.y)) + 0.9f * qv0.y;
    o0.z = 0.1f * (0.25f * (acc[2] + bs0.z)) + 0.9f * qv0.z;
    o0.w = 0.1f * (0.25f * (acc[3] + bs0.w)) + 0.9f * qv0.w;
    o1.x = 0.1f * (0.25f * (acc[4] + bs1.x)) + 0.9f * qv1.x;
    o1.y = 0.1f * (0.25f * (acc[5] + bs1.y)) + 0.9f * qv1.y;
    o1.z = 0.1f * (0.25f * (acc[6] + bs1.z)) + 0.9f * qv1.z;
    o1.w = 0.1f * (0.25f * (acc[7] + bs1.w)) + 0.9f * qv1.w;
    *(float4*)(nq + qi)     = o0;
    *(float4*)(nq + qi + 4) = o1;
}

// ---------------- conv GEMM via bf16 MFMA (BK=64, FULL N-tile) ----------------
// nv[m][o] = sum_kk nq[m*1152+kk] * convT2[o][kk] + conv_b[o]
// Tile M=32 x N=128 (grid 259x1): nq read ONCE (38MB, was 76MB at N-split=2).
// 4 waves, each owns 32 cols; acc[2][2] = 2 M-frags x 2 N-frags.
__global__ __launch_bounds__(256) void conv_mfma_k(
    const float* __restrict__ nq, const unsigned short* __restrict__ convT2,
    const float* __restrict__ conv_b, float* __restrict__ nv)
{
    __shared__ unsigned short As[32][72];    // [m][k] BK=64, pad->72
    __shared__ unsigned short Bs[128][72];   // [n][k]

    const int tid  = threadIdx.x;
    const int lane = tid & 63;
    const int wave = tid >> 6;
    const int m0 = blockIdx.x * 32;
    const int l15  = lane & 15;
    const int quad = lane >> 4;

    floatx4 acc[2][2];   // [mf][nt]
    #pragma unroll
    for (int mf = 0; mf < 2; ++mf)
        #pragma unroll
        for (int nt = 0; nt < 2; ++nt) acc[mf][nt] = (floatx4){0.f, 0.f, 0.f, 0.f};

    const int am = tid >> 3;             // 0..31
    const int ak = (tid & 7) << 3;       // 0,8,..,56
    const int bn = tid >> 1;             // 0..127
    const int bk = (tid & 1) << 5;       // 0,32 (shorts)

    float4 a0, a1; uint4 bv0, bv1, bv2, bv3;
    auto fetch = [&](int k0) {
        a0 = (float4){0,0,0,0}; a1 = a0;
        int row = m0 + am;
        if (row < M_CONV) {
            a0 = *(const float4*)(nq + (long)row * 1152 + k0 + ak);
            a1 = *(const float4*)(nq + (long)row * 1152 + k0 + ak + 4);
        }
        const unsigned short* bp = convT2 + (long)bn * 1152 + k0 + bk;
        bv0 = *(const uint4*)(bp);
        bv1 = *(const uint4*)(bp + 8);
        bv2 = *(const uint4*)(bp + 16);
        bv3 = *(const uint4*)(bp + 24);
    };
    fetch(0);

    for (int k0 = 0; k0 < 1152; k0 += 64) {
        unsigned short t[8] = {f2bf_rne(a0.x), f2bf_rne(a0.y), f2bf_rne(a0.z), f2bf_rne(a0.w),
                               f2bf_rne(a1.x), f2bf_rne(a1.y), f2bf_rne(a1.z), f2bf_rne(a1.w)};
        *(uint4*)&As[am][ak] = *(const uint4*)t;
        *(uint4*)&Bs[bn][bk]      = bv0;
        *(uint4*)&Bs[bn][bk + 8]  = bv1;
        *(uint4*)&Bs[bn][bk + 16] = bv2;
        *(uint4*)&Bs[bn][bk + 24] = bv3;
        __syncthreads();
        if (k0 + 64 < 1152) fetch(k0 + 64);

        #pragma unroll
        for (int kt = 0; kt < 2; ++kt) {
            short8 af0 = *(const short8*)&As[l15][kt * 32 + quad * 8];
            short8 af1 = *(const short8*)&As[16 + l15][kt * 32 + quad * 8];
            #pragma unroll
            for (int nt = 0; nt < 2; ++nt) {
                short8 bf = *(const short8*)&Bs[wave * 32 + nt * 16 + l15][kt * 32 + quad * 8];
                acc[0][nt] = __builtin_amdgcn_mfma_f32_16x16x32_bf16(af0, bf, acc[0][nt], 0, 0, 0);
                acc[1][nt] = __builtin_amdgcn_mfma_f32_16x16x32_bf16(af1, bf, acc[1][nt], 0, 0, 0);
            }
        }
        __syncthreads();
    }

    #pragma unroll
    for (int nt = 0; nt < 2; ++nt) {
        const int col = wave * 32 + nt * 16 + l15;
        const float bias = conv_b[col];
        #pragma unroll
        for (int mf = 0; mf < 2; ++mf) {
            #pragma unroll
            for (int r = 0; r < 4; ++r) {
                int row = m0 + mf * 16 + quad * 4 + r;
                if (row < M_CONV)
                    nv[(long)row * 128 + col] = acc[mf][nt][r] + bias;
            }
        }
    }
}

extern "C" void kernel_launch(void* const* d_in, const int* in_sizes, int n_in,
                              void* d_out, int out_size, void* d_ws, size_t ws_size,
                              hipStream_t stream) {
    const float* f0     = (const float*)d_in[0];
    const float* f1     = (const float*)d_in[1];
    const float* f2     = (const float*)d_in[2];
    const float* f3     = (const float*)d_in[3];
    const float* query  = (const float*)d_in[4];
    const float* key    = (const float*)d_in[5];
    const float* value  = (const float*)d_in[6];
    const float* w_off  = (const float*)d_in[7];
    const float* b_off  = (const float*)d_in[8];
    const float* w_attn = (const float*)d_in[9];
    const float* b_attn = (const float*)d_in[10];
    const float* we0    = (const float*)d_in[11];
    const float* be0    = (const float*)d_in[12];
    const float* we1    = (const float*)d_in[13];
    const float* be1    = (const float*)d_in[14];
    const float* we2    = (const float*)d_in[15];
    const float* be2    = (const float*)d_in[16];
    const float* we3    = (const float*)d_in[17];
    const float* be3    = (const float*)d_in[18];
    const float* conv_w = (const float*)d_in[19];
    const float* conv_b = (const float*)d_in[20];

    float* out  = (float*)d_out;
    float* nq   = out;                       // new_query
    float* nv   = out + NQ_SIZE;             // new_value
    float* samp = out + NQ_SIZE + NV_SIZE;   // sampling_positions

    // ws layout: E maps (bf16, 21,150,720) | convT2 (bf16, 147,456)
    unsigned short* Ebase  = (unsigned short*)d_ws;
    unsigned short* convT2 = Ebase + E_END;
    // scratch tables live in the nv output region; conv_mfma_k overwrites nv
    // LAST, after gather_k has consumed them.
    float* awbuf = nv;                 // 486*17*2 floats
    float* besum = nv + 16524;         // 128 floats

    // 1. fused prep: projections (MFMA, JIT-A, LDS epilogue) + aw + convT2 + besum
    prep_k<<<PREP_GRID, 256, 0, stream>>>(
        f0, f1, f2, f3, we0, we1, we2, we3, conv_w, convT2,
        value, w_attn, b_attn, be0, be1, be2, be3, awbuf, besum, Ebase);

    // 2. gather + inline sampling + mean + blend -> new_query, samp (4648 blocks)
    gather_k<<<4648, 256, 0, stream>>>(
        Ebase, query, key, w_off, b_off, awbuf, besum, nq, samp);

    // 3. new_value GEMM via MFMA: M=8262, K=1152, N=128, full N-tile (259 blocks)
    conv_mfma_k<<<259, 256, 0, stream>>>(nq, convT2, conv_b, nv);
}